// Round 1
// baseline (2487.107 us; speedup 1.0000x reference)
//
#include <hip/hip_runtime.h>
#include <math.h>

// Problem constants (fixed by setup_inputs)
#define B_    4
#define C_    64
#define H_    380
#define W_    380
#define HW_   (H_ * W_)        // 144400
#define NPIX_ (B_ * HW_)       // 577600

// Table layout inside tabs[] (floats)
#define TAB_QPE 0
#define TAB_KPE 576
#define TAB_VPE 1152
#define TAB_CC  1728
#define TAB_SZ  (1728 + 81)

__device__ __forceinline__ void fma4(float4& o, float s, const float4 v) {
    o.x = fmaf(s, v.x, o.x);
    o.y = fmaf(s, v.y, o.y);
    o.z = fmaf(s, v.z, o.z);
    o.w = fmaf(s, v.w, o.w);
}

__device__ __forceinline__ void dot4(float& a0, float& a1, float& a2, float& a3,
                                     const float4 q, const float4 k) {
    a0 = fmaf(q.x, k.x, a0);
    a1 = fmaf(q.y, k.y, a1);
    a2 = fmaf(q.z, k.z, a2);
    a3 = fmaf(q.w, k.w, a3);
}

// ---------------------------------------------------------------------------
// Kernel 0: positional-encoding derived tables.
//   qpe[t] = pe[t]@WqT + bq ; kpe, vpe likewise ; Cc[p][q] = qpe[p]·kpe[q]
// ---------------------------------------------------------------------------
__global__ __launch_bounds__(64) void tab_kernel(
    const float* __restrict__ Wq, const float* __restrict__ bq,
    const float* __restrict__ Wk, const float* __restrict__ bk,
    const float* __restrict__ Wv, const float* __restrict__ bv,
    float* __restrict__ tabs)
{
    __shared__ float pe[576];
    __shared__ float qs[576];
    __shared__ float ks[576];
    const int t = threadIdx.x;   // 64 threads, t = out channel

    for (int idx = t; idx < 576; idx += 64) {
        const int pos = idx >> 6;
        const int c   = idx & 63;
        const int m   = c >> 1;
        // reference: angle = pos / 10000^( (2*dims)/C ), dims = 2m -> exp = m/16
        const double ang = (double)pos / pow(10000.0, (double)m / 16.0);
        pe[idx] = (float)((c & 1) ? cos(ang) : sin(ang));
    }
    __syncthreads();

    for (int pos = 0; pos < 9; ++pos) {
        float aq = bq[t], ak = bk[t], av = bv[t];
        for (int c = 0; c < 64; ++c) {
            const float p = pe[pos * 64 + c];
            aq = fmaf(p, Wq[t * 64 + c], aq);
            ak = fmaf(p, Wk[t * 64 + c], ak);
            av = fmaf(p, Wv[t * 64 + c], av);
        }
        qs[pos * 64 + t] = aq;
        ks[pos * 64 + t] = ak;
        tabs[TAB_QPE + pos * 64 + t] = aq;
        tabs[TAB_KPE + pos * 64 + t] = ak;
        tabs[TAB_VPE + pos * 64 + t] = av;
    }
    __syncthreads();

    for (int idx = t; idx < 81; idx += 64) {
        const int p = idx / 9;
        const int q = idx - p * 9;
        float a = 0.f;
        for (int c = 0; c < 64; ++c) a = fmaf(qs[p * 64 + c], ks[q * 64 + c], a);
        tabs[TAB_CC + idx] = a;
    }
}

// ---------------------------------------------------------------------------
// Kernel 1: per-pixel projections (no bias; bias folded into pe tables).
//   Xq/Xk/Xv pixel-major [n][64]; Bk[n][12] = qpe[p]·Xk[n] (p=0..8, 3 pad);
//   also copies x into out channels [0,64).
//   Thread = one pixel. W / qpe accessed at wave-uniform addresses -> s_loads.
// ---------------------------------------------------------------------------
__global__ __launch_bounds__(256) void proj_kernel(
    const float* __restrict__ x,
    const float* __restrict__ Wq, const float* __restrict__ Wk,
    const float* __restrict__ Wv,
    const float* __restrict__ tabs,
    float* __restrict__ Xq, float* __restrict__ Xk, float* __restrict__ Xv,
    float* __restrict__ Bkv, float* __restrict__ out)
{
    const int n = blockIdx.x * 256 + threadIdx.x;
    if (n >= NPIX_) return;
    const int b  = n / HW_;
    const int hw = n - b * HW_;

    const float* xp = x + (size_t)b * 64 * HW_ + hw;
    float f[64];
#pragma unroll
    for (int c = 0; c < 64; ++c) f[c] = xp[(size_t)c * HW_];

    // passthrough copy: out channels [0,64)
    float* op = out + (size_t)b * 128 * HW_ + hw;
#pragma unroll
    for (int c = 0; c < 64; ++c) op[(size_t)c * HW_] = f[c];

    // ---- Xq ----
    {
        float* Dp = Xq + ((size_t)n << 6);
        for (int oc4 = 0; oc4 < 16; ++oc4) {
            float r[4];
#pragma unroll
            for (int j = 0; j < 4; ++j) {
                const float* wr = Wq + (oc4 * 4 + j) * 64;
                float a0 = 0.f, a1 = 0.f, a2 = 0.f, a3 = 0.f;
#pragma unroll
                for (int c = 0; c < 64; c += 4) {
                    a0 = fmaf(f[c + 0], wr[c + 0], a0);
                    a1 = fmaf(f[c + 1], wr[c + 1], a1);
                    a2 = fmaf(f[c + 2], wr[c + 2], a2);
                    a3 = fmaf(f[c + 3], wr[c + 3], a3);
                }
                r[j] = (a0 + a1) + (a2 + a3);
            }
            *(float4*)(Dp + (oc4 << 2)) = make_float4(r[0], r[1], r[2], r[3]);
        }
    }
    // ---- Xk (+ Bk = qpe[p]·Xk) ----
    {
        float* Dp = Xk + ((size_t)n << 6);
        float bkacc[9];
#pragma unroll
        for (int p = 0; p < 9; ++p) bkacc[p] = 0.f;
        for (int oc4 = 0; oc4 < 16; ++oc4) {
            float r[4];
#pragma unroll
            for (int j = 0; j < 4; ++j) {
                const float* wr = Wk + (oc4 * 4 + j) * 64;
                float a0 = 0.f, a1 = 0.f, a2 = 0.f, a3 = 0.f;
#pragma unroll
                for (int c = 0; c < 64; c += 4) {
                    a0 = fmaf(f[c + 0], wr[c + 0], a0);
                    a1 = fmaf(f[c + 1], wr[c + 1], a1);
                    a2 = fmaf(f[c + 2], wr[c + 2], a2);
                    a3 = fmaf(f[c + 3], wr[c + 3], a3);
                }
                r[j] = (a0 + a1) + (a2 + a3);
#pragma unroll
                for (int p = 0; p < 9; ++p)
                    bkacc[p] = fmaf(tabs[TAB_QPE + p * 64 + oc4 * 4 + j], r[j], bkacc[p]);
            }
            *(float4*)(Dp + (oc4 << 2)) = make_float4(r[0], r[1], r[2], r[3]);
        }
        float* Bp = Bkv + (size_t)n * 12;
        *(float4*)(Bp + 0) = make_float4(bkacc[0], bkacc[1], bkacc[2], bkacc[3]);
        *(float4*)(Bp + 4) = make_float4(bkacc[4], bkacc[5], bkacc[6], bkacc[7]);
        *(float4*)(Bp + 8) = make_float4(bkacc[8], 0.f, 0.f, 0.f);
    }
    // ---- Xv ----
    {
        float* Dp = Xv + ((size_t)n << 6);
        for (int oc4 = 0; oc4 < 16; ++oc4) {
            float r[4];
#pragma unroll
            for (int j = 0; j < 4; ++j) {
                const float* wr = Wv + (oc4 * 4 + j) * 64;
                float a0 = 0.f, a1 = 0.f, a2 = 0.f, a3 = 0.f;
#pragma unroll
                for (int c = 0; c < 64; c += 4) {
                    a0 = fmaf(f[c + 0], wr[c + 0], a0);
                    a1 = fmaf(f[c + 1], wr[c + 1], a1);
                    a2 = fmaf(f[c + 2], wr[c + 2], a2);
                    a3 = fmaf(f[c + 3], wr[c + 3], a3);
                }
                r[j] = (a0 + a1) + (a2 + a3);
            }
            *(float4*)(Dp + (oc4 << 2)) = make_float4(r[0], r[1], r[2], r[3]);
        }
    }
}

// ---------------------------------------------------------------------------
// Kernel 2: fused sliding-patch attention, gather form.
//   Block = 16x16 output pixels, thread = one pixel.
//   Phase 1: stage Xk halo (20 rows x 21 cols, XOR-swizzled) + Bk; D[25] dots;
//            Aq[9] = Xq·kpe; 9 softmax rows -> Wt[25], Sq[9].
//   Phase 2: restage halo with Xv; o = sum_d Wt[d]*Xv[P+d] + sum_q Sq[q]*vpe[q];
//            o /= coverage count; write out channels [64,128).
// ---------------------------------------------------------------------------
#define HALO_ROWS 20
#define HALO_COLS 21      // 20 used + 1 pad so ty->nb stride is 21 (odd-ish spread)
#define HALO_N    (HALO_ROWS * HALO_COLS)   // 420

__global__ __launch_bounds__(256) void attn_kernel(
    const float* __restrict__ Xq, const float* __restrict__ Xk,
    const float* __restrict__ Xv, const float* __restrict__ Bkv,
    const float* __restrict__ tabs, float* __restrict__ out)
{
    __shared__ __align__(16) float sKV[HALO_N * 64];   // 107,520 B
    __shared__ __align__(16) float sB[HALO_N * 12];    //  20,160 B

    const int b   = blockIdx.z;
    const int h0  = blockIdx.y * 16;
    const int w0  = blockIdx.x * 16;
    const int tid = threadIdx.x;
    const int ty  = tid >> 4;
    const int tx  = tid & 15;
    const int h   = h0 + ty;
    const int w   = w0 + tx;
    const bool act = (h < H_) && (w < W_);
    const int bBase = b * HW_;

    const float* kpe = tabs + TAB_KPE;
    const float* vpe = tabs + TAB_VPE;
    const float* Cc  = tabs + TAB_CC;

    // ---- stage Xk halo (swizzled: chunk c4 stored at slot c4^(nb&7)) ----
    for (int idx = tid; idx < HALO_N * 16; idx += 256) {
        const int nb = idx >> 4, c4 = idx & 15;
        const int hr = nb / HALO_COLS, hc = nb - hr * HALO_COLS;
        const int gh = min(max(h0 - 2 + hr, 0), H_ - 1);
        const int gw = min(max(w0 - 2 + hc, 0), W_ - 1);
        const float4 v = *(const float4*)(Xk + ((size_t)(bBase + gh * W_ + gw) << 6) + (c4 << 2));
        *(float4*)(sKV + nb * 64 + ((c4 ^ (nb & 7)) << 2)) = v;
    }
    // ---- stage Bk halo ----
    for (int idx = tid; idx < HALO_N * 3; idx += 256) {
        const int nb = idx / 3, q4 = idx - nb * 3;
        const int hr = nb / HALO_COLS, hc = nb - hr * HALO_COLS;
        const int gh = min(max(h0 - 2 + hr, 0), H_ - 1);
        const int gw = min(max(w0 - 2 + hc, 0), W_ - 1);
        *(float4*)(sB + nb * 12 + (q4 << 2)) =
            *(const float4*)(Bkv + (size_t)(bBase + gh * W_ + gw) * 12 + (q4 << 2));
    }

    // own-pixel Xq into registers
    float4 xq[16];
    if (act) {
        const float* qp = Xq + ((size_t)(bBase + h * W_ + w) << 6);
#pragma unroll
        for (int c4 = 0; c4 < 16; ++c4) xq[c4] = ((const float4*)qp)[c4];
    }
    __syncthreads();

    // ---- D[25] = Xq·Xk[P+δ] ; Aq[9] = Xq·kpe[q] ----
    float D[25];
    float Aq[9];
    if (act) {
#pragma unroll
        for (int dh = 0; dh < 5; ++dh) {
#pragma unroll
            for (int dw = 0; dw < 5; ++dw) {
                const int nb = (ty + dh) * HALO_COLS + (tx + dw);
                const int kk = nb & 7;
                const float* kb = sKV + nb * 64;
                float a0 = 0.f, a1 = 0.f, a2 = 0.f, a3 = 0.f;
#pragma unroll
                for (int c4 = 0; c4 < 16; ++c4) {
                    const float4 kv = *(const float4*)(kb + ((c4 ^ kk) << 2));
                    dot4(a0, a1, a2, a3, xq[c4], kv);
                }
                D[dh * 5 + dw] = (a0 + a1) + (a2 + a3);
            }
        }
#pragma unroll
        for (int q = 0; q < 9; ++q) {
            float a0 = 0.f, a1 = 0.f, a2 = 0.f, a3 = 0.f;
#pragma unroll
            for (int c4 = 0; c4 < 16; ++c4) {
                const float4 kp = *(const float4*)(kpe + q * 64 + (c4 << 2));
                dot4(a0, a1, a2, a3, xq[c4], kp);
            }
            Aq[q] = (a0 + a1) + (a2 + a3);
        }
    }

    // ---- logits -> softmax rows -> Wt[25], Sq[9] ----
    float Wt[25];
    float Sq[9];
#pragma unroll
    for (int i = 0; i < 25; ++i) Wt[i] = 0.f;
#pragma unroll
    for (int i = 0; i < 9; ++i) Sq[i] = 0.f;

    if (act) {
#pragma unroll
        for (int ph = 0; ph < 3; ++ph) {
#pragma unroll
            for (int pw = 0; pw < 3; ++pw) {
                // patch top-left (h-ph, w-pw) must lie in [0, H-3] x [0, W-3]
                if ((h >= ph) && (h <= (H_ - 3) + ph) && (w >= pw) && (w <= (W_ - 3) + pw)) {
                    const int p = ph * 3 + pw;
                    float l[9];
                    float m = -1e30f;
#pragma unroll
                    for (int qh = 0; qh < 3; ++qh) {
#pragma unroll
                        for (int qw = 0; qw < 3; ++qw) {
                            const int q  = qh * 3 + qw;
                            const int nb = (ty + 2 + qh - ph) * HALO_COLS + (tx + 2 + qw - pw);
                            const float lv = D[(qh - ph + 2) * 5 + (qw - pw + 2)]
                                           + Aq[q] + sB[nb * 12 + p] + Cc[p * 9 + q];
                            l[q] = lv;
                            m = fmaxf(m, lv);
                        }
                    }
                    float e[9];
                    float s = 0.f;
#pragma unroll
                    for (int q = 0; q < 9; ++q) { e[q] = __expf(l[q] - m); s += e[q]; }
                    const float inv = 1.0f / s;
#pragma unroll
                    for (int qh = 0; qh < 3; ++qh) {
#pragma unroll
                        for (int qw = 0; qw < 3; ++qw) {
                            const int q = qh * 3 + qw;
                            const float t = e[q] * inv;
                            Wt[(qh - ph + 2) * 5 + (qw - pw + 2)] += t;
                            Sq[q] += t;
                        }
                    }
                }
            }
        }
    }

    __syncthreads();
    // ---- restage halo with Xv ----
    for (int idx = tid; idx < HALO_N * 16; idx += 256) {
        const int nb = idx >> 4, c4 = idx & 15;
        const int hr = nb / HALO_COLS, hc = nb - hr * HALO_COLS;
        const int gh = min(max(h0 - 2 + hr, 0), H_ - 1);
        const int gw = min(max(w0 - 2 + hc, 0), W_ - 1);
        const float4 v = *(const float4*)(Xv + ((size_t)(bBase + gh * W_ + gw) << 6) + (c4 << 2));
        *(float4*)(sKV + nb * 64 + ((c4 ^ (nb & 7)) << 2)) = v;
    }
    __syncthreads();

    if (act) {
        float4 o[16];
#pragma unroll
        for (int c4 = 0; c4 < 16; ++c4) o[c4] = make_float4(0.f, 0.f, 0.f, 0.f);

        // 25-tap weighted neighborhood sum of Xv
#pragma unroll
        for (int dh = 0; dh < 5; ++dh) {
#pragma unroll
            for (int dw = 0; dw < 5; ++dw) {
                const float wt = Wt[dh * 5 + dw];
                const int nb = (ty + dh) * HALO_COLS + (tx + dw);
                const int kk = nb & 7;
                const float* vb = sKV + nb * 64;
#pragma unroll
                for (int c4 = 0; c4 < 16; ++c4) {
                    const float4 vv = *(const float4*)(vb + ((c4 ^ kk) << 2));
                    fma4(o[c4], wt, vv);
                }
            }
        }
        // + Sq-weighted vpe rows
#pragma unroll
        for (int q = 0; q < 9; ++q) {
            const float sq = Sq[q];
#pragma unroll
            for (int c4 = 0; c4 < 16; ++c4) {
                const float4 vp = *(const float4*)(vpe + q * 64 + (c4 << 2));
                fma4(o[c4], sq, vp);
            }
        }

        const int ch = min(h, H_ - 3) - max(0, h - 2) + 1;
        const int cw = min(w, W_ - 3) - max(0, w - 2) + 1;
        const float invN = 1.0f / (float)(ch * cw);

        float* ob = out + ((size_t)b * 128 + 64) * HW_ + h * W_ + w;
#pragma unroll
        for (int c4 = 0; c4 < 16; ++c4) {
            ob[(size_t)(c4 * 4 + 0) * HW_] = o[c4].x * invN;
            ob[(size_t)(c4 * 4 + 1) * HW_] = o[c4].y * invN;
            ob[(size_t)(c4 * 4 + 2) * HW_] = o[c4].z * invN;
            ob[(size_t)(c4 * 4 + 3) * HW_] = o[c4].w * invN;
        }
    }
}

// ---------------------------------------------------------------------------
extern "C" void kernel_launch(void* const* d_in, const int* in_sizes, int n_in,
                              void* d_out, int out_size, void* d_ws, size_t ws_size,
                              hipStream_t stream)
{
    const float* x  = (const float*)d_in[0];
    const float* Wq = (const float*)d_in[1];
    const float* bq = (const float*)d_in[2];
    const float* Wk = (const float*)d_in[3];
    const float* bk = (const float*)d_in[4];
    const float* Wv = (const float*)d_in[5];
    const float* bv = (const float*)d_in[6];
    float* out = (float*)d_out;

    float* ws  = (float*)d_ws;
    float* Xq  = ws;
    float* Xk  = ws + (size_t)NPIX_ * 64;
    float* Xv  = ws + (size_t)NPIX_ * 64 * 2;
    float* Bkv = ws + (size_t)NPIX_ * 64 * 3;
    float* tabs = Bkv + (size_t)NPIX_ * 12;
    // total ws need: (3*64 + 12)*NPIX_ + TAB_SZ floats ≈ 471.3 MB

    tab_kernel<<<1, 64, 0, stream>>>(Wq, bq, Wk, bk, Wv, bv, tabs);

    proj_kernel<<<(NPIX_ + 255) / 256, 256, 0, stream>>>(
        x, Wq, Wk, Wv, tabs, Xq, Xk, Xv, Bkv, out);

    attn_kernel<<<dim3((W_ + 15) / 16, (H_ + 15) / 16, B_), 256, 0, stream>>>(
        Xq, Xk, Xv, Bkv, tabs, out);
}

// Round 2
// 1547.621 us; speedup vs baseline: 1.6071x; 1.6071x over previous
//
#include <hip/hip_runtime.h>
#include <math.h>

// Problem constants (fixed by setup_inputs)
#define B_    4
#define C_    64
#define H_    380
#define W_    380
#define HW_   (H_ * W_)        // 144400
#define NPIX_ (B_ * HW_)       // 577600

// Table layout inside tabs[] (floats)
#define TAB_QPE 0
#define TAB_KPE 576
#define TAB_VPE 1152
#define TAB_CC  1728
#define TAB_SZ  (1728 + 81)

// mega-kernel tiling
#define HALO_ROWS 20
#define HALO_COLS 21           // 20 used + 1 pad
#define HALO_N    (HALO_ROWS * HALO_COLS)   // 420
#define CHUNK     16           // channels per LDS pass
#define NCHUNK    4

__device__ __forceinline__ void fma4(float4& o, float s, const float4 v) {
    o.x = fmaf(s, v.x, o.x);
    o.y = fmaf(s, v.y, o.y);
    o.z = fmaf(s, v.z, o.z);
    o.w = fmaf(s, v.w, o.w);
}

// ---------------------------------------------------------------------------
// Kernel 0: positional-encoding derived tables.
//   qpe[t] = pe[t]@WqT + bq ; kpe, vpe likewise ; Cc[p][q] = qpe[p]·kpe[q]
// ---------------------------------------------------------------------------
__global__ __launch_bounds__(64) void tab_kernel(
    const float* __restrict__ Wq, const float* __restrict__ bq,
    const float* __restrict__ Wk, const float* __restrict__ bk,
    const float* __restrict__ Wv, const float* __restrict__ bv,
    float* __restrict__ tabs)
{
    __shared__ float pe[576];
    __shared__ float qs[576];
    __shared__ float ks[576];
    const int t = threadIdx.x;   // 64 threads, t = out channel

    for (int idx = t; idx < 576; idx += 64) {
        const int pos = idx >> 6;
        const int c   = idx & 63;
        const int m   = c >> 1;
        const double ang = (double)pos / pow(10000.0, (double)m / 16.0);
        pe[idx] = (float)((c & 1) ? cos(ang) : sin(ang));
    }
    __syncthreads();

    for (int pos = 0; pos < 9; ++pos) {
        float aq = bq[t], ak = bk[t], av = bv[t];
        for (int c = 0; c < 64; ++c) {
            const float p = pe[pos * 64 + c];
            aq = fmaf(p, Wq[t * 64 + c], aq);
            ak = fmaf(p, Wk[t * 64 + c], ak);
            av = fmaf(p, Wv[t * 64 + c], av);
        }
        qs[pos * 64 + t] = aq;
        ks[pos * 64 + t] = ak;
        tabs[TAB_QPE + pos * 64 + t] = aq;
        tabs[TAB_KPE + pos * 64 + t] = ak;
        tabs[TAB_VPE + pos * 64 + t] = av;
    }
    __syncthreads();

    for (int idx = t; idx < 81; idx += 64) {
        const int p = idx / 9;
        const int q = idx - p * 9;
        float a = 0.f;
        for (int c = 0; c < 64; ++c) a = fmaf(qs[p * 64 + c], ks[q * 64 + c], a);
        tabs[TAB_CC + idx] = a;
    }
}

// ---------------------------------------------------------------------------
// Kernel 1: per-pixel K/V projections (bias folded into pe tables).
//   Xk/Xv pixel-major [n][64]; Bk[n][12] = qpe[p]·Xk[n] (p=0..8, 3 pad);
//   also copies x into out channels [0,64). No Q output (mega recomputes it).
// ---------------------------------------------------------------------------
__global__ __launch_bounds__(256) void proj_kernel(
    const float* __restrict__ x,
    const float* __restrict__ Wk, const float* __restrict__ Wv,
    const float* __restrict__ tabs,
    float* __restrict__ Xk, float* __restrict__ Xv,
    float* __restrict__ Bkv, float* __restrict__ out)
{
    const int n = blockIdx.x * 256 + threadIdx.x;
    if (n >= NPIX_) return;
    const int b  = n / HW_;
    const int hw = n - b * HW_;

    const float* xp = x + (size_t)b * 64 * HW_ + hw;
    float f[64];
#pragma unroll
    for (int c = 0; c < 64; ++c) f[c] = xp[(size_t)c * HW_];

    // passthrough copy: out channels [0,64)
    float* op = out + (size_t)b * 128 * HW_ + hw;
#pragma unroll
    for (int c = 0; c < 64; ++c) op[(size_t)c * HW_] = f[c];

    // ---- Xk (+ Bk = qpe[p]·Xk) ----
    {
        float* Dp = Xk + ((size_t)n << 6);
        float bkacc[9];
#pragma unroll
        for (int p = 0; p < 9; ++p) bkacc[p] = 0.f;
        for (int oc4 = 0; oc4 < 16; ++oc4) {
            float r[4];
#pragma unroll
            for (int j = 0; j < 4; ++j) {
                const float* wr = Wk + (oc4 * 4 + j) * 64;
                float a0 = 0.f, a1 = 0.f, a2 = 0.f, a3 = 0.f;
#pragma unroll
                for (int c = 0; c < 64; c += 4) {
                    a0 = fmaf(f[c + 0], wr[c + 0], a0);
                    a1 = fmaf(f[c + 1], wr[c + 1], a1);
                    a2 = fmaf(f[c + 2], wr[c + 2], a2);
                    a3 = fmaf(f[c + 3], wr[c + 3], a3);
                }
                r[j] = (a0 + a1) + (a2 + a3);
#pragma unroll
                for (int p = 0; p < 9; ++p)
                    bkacc[p] = fmaf(tabs[TAB_QPE + p * 64 + oc4 * 4 + j], r[j], bkacc[p]);
            }
            *(float4*)(Dp + (oc4 << 2)) = make_float4(r[0], r[1], r[2], r[3]);
        }
        float* Bp = Bkv + (size_t)n * 12;
        *(float4*)(Bp + 0) = make_float4(bkacc[0], bkacc[1], bkacc[2], bkacc[3]);
        *(float4*)(Bp + 4) = make_float4(bkacc[4], bkacc[5], bkacc[6], bkacc[7]);
        *(float4*)(Bp + 8) = make_float4(bkacc[8], 0.f, 0.f, 0.f);
    }
    // ---- Xv ----
    {
        float* Dp = Xv + ((size_t)n << 6);
        for (int oc4 = 0; oc4 < 16; ++oc4) {
            float r[4];
#pragma unroll
            for (int j = 0; j < 4; ++j) {
                const float* wr = Wv + (oc4 * 4 + j) * 64;
                float a0 = 0.f, a1 = 0.f, a2 = 0.f, a3 = 0.f;
#pragma unroll
                for (int c = 0; c < 64; c += 4) {
                    a0 = fmaf(f[c + 0], wr[c + 0], a0);
                    a1 = fmaf(f[c + 1], wr[c + 1], a1);
                    a2 = fmaf(f[c + 2], wr[c + 2], a2);
                    a3 = fmaf(f[c + 3], wr[c + 3], a3);
                }
                r[j] = (a0 + a1) + (a2 + a3);
            }
            *(float4*)(Dp + (oc4 << 2)) = make_float4(r[0], r[1], r[2], r[3]);
        }
    }
}

// ---------------------------------------------------------------------------
// Kernel 2: fused dots + softmax + PV, channel-chunked LDS.
//   Block = 16x16 pixels. LDS: sK[420][16] chunk buffer (26,880B, Xk then Xv)
//   + sBT[9][420] (15,120B). Total 42,000B -> 3 blocks/CU.
//   Phase 1 (x4 chunks): xq chunk from f (regs), stage Xk chunk, D[25] & Aq[9].
//   Softmax: 9 patches -> Wt[25], Sq[9].
//   Phase 2 (x4 chunks): stage Xv chunk, o[16] = taps + vpe, write out.
// ---------------------------------------------------------------------------
__global__ __launch_bounds__(256) void mega_kernel(
    const float* __restrict__ x,   const float* __restrict__ Wq,
    const float* __restrict__ Xk,  const float* __restrict__ Xv,
    const float* __restrict__ Bkv, const float* __restrict__ tabs,
    float* __restrict__ out)
{
    __shared__ __align__(16) float sK[HALO_N * CHUNK];   // 26,880 B
    __shared__ float sBT[9 * HALO_N];                    // 15,120 B

    const int b   = blockIdx.z;
    const int h0  = blockIdx.y * 16;
    const int w0  = blockIdx.x * 16;
    const int tid = threadIdx.x;
    const int ty  = tid >> 4;
    const int tx  = tid & 15;
    const int h   = h0 + ty;
    const int w   = w0 + tx;
    const bool act = (h < H_) && (w < W_);
    const int bBase = b * HW_;

    const float* kpe = tabs + TAB_KPE;
    const float* vpe = tabs + TAB_VPE;
    const float* Cc  = tabs + TAB_CC;

    // ---- stage Bk transposed: sBT[p][nb] ----
    for (int idx = tid; idx < 9 * HALO_N; idx += 256) {
        const int p  = idx / HALO_N;
        const int nb = idx - p * HALO_N;
        const int hr = nb / HALO_COLS, hc = nb - hr * HALO_COLS;
        const int gh = min(max(h0 - 2 + hr, 0), H_ - 1);
        const int gw = min(max(w0 - 2 + hc, 0), W_ - 1);
        sBT[idx] = Bkv[(size_t)(bBase + gh * W_ + gw) * 12 + p];
    }

    // ---- own-pixel features ----
    float f[64];
    if (act) {
        const float* xp = x + (size_t)b * 64 * HW_ + h * W_ + w;
#pragma unroll
        for (int c = 0; c < 64; ++c) f[c] = xp[(size_t)c * HW_];
    } else {
#pragma unroll
        for (int c = 0; c < 64; ++c) f[c] = 0.f;
    }

    float D[25];
    float Aq[9];
#pragma unroll
    for (int i = 0; i < 25; ++i) D[i] = 0.f;
#pragma unroll
    for (int i = 0; i < 9; ++i) Aq[i] = 0.f;

    // ================= Phase 1: dots, channel-chunked =================
    for (int cc = 0; cc < NCHUNK; ++cc) {
        // xq chunk = Wq rows [cc*16, cc*16+16) · f   (weights via s_loads)
        float xqc[CHUNK];
#pragma unroll
        for (int j = 0; j < CHUNK; ++j) {
            const float* wr = Wq + (cc * CHUNK + j) * 64;
            float a0 = 0.f, a1 = 0.f, a2 = 0.f, a3 = 0.f;
#pragma unroll
            for (int c = 0; c < 64; c += 4) {
                a0 = fmaf(f[c + 0], wr[c + 0], a0);
                a1 = fmaf(f[c + 1], wr[c + 1], a1);
                a2 = fmaf(f[c + 2], wr[c + 2], a2);
                a3 = fmaf(f[c + 3], wr[c + 3], a3);
            }
            xqc[j] = (a0 + a1) + (a2 + a3);
        }

        __syncthreads();   // previous chunk's consumers done with sK
        for (int idx = tid; idx < HALO_N * 4; idx += 256) {
            const int nb = idx >> 2, s = idx & 3;
            const int hr = nb / HALO_COLS, hc = nb - hr * HALO_COLS;
            const int gh = min(max(h0 - 2 + hr, 0), H_ - 1);
            const int gw = min(max(w0 - 2 + hc, 0), W_ - 1);
            const float4 v = *(const float4*)(Xk + ((size_t)(bBase + gh * W_ + gw) << 6)
                                              + cc * CHUNK + (s << 2));
            *(float4*)(sK + nb * CHUNK + (((s ^ nb) & 3) << 2)) = v;
        }
        __syncthreads();

        if (act) {
#pragma unroll
            for (int dh = 0; dh < 5; ++dh) {
#pragma unroll
                for (int dw = 0; dw < 5; ++dw) {
                    const int nb = (ty + dh) * HALO_COLS + (tx + dw);
                    const int kk = nb & 3;
                    const float* kb = sK + nb * CHUNK;
                    float a0 = 0.f, a1 = 0.f, a2 = 0.f, a3 = 0.f;
#pragma unroll
                    for (int c4 = 0; c4 < 4; ++c4) {
                        const float4 kv = *(const float4*)(kb + ((c4 ^ kk) << 2));
                        a0 = fmaf(xqc[c4 * 4 + 0], kv.x, a0);
                        a1 = fmaf(xqc[c4 * 4 + 1], kv.y, a1);
                        a2 = fmaf(xqc[c4 * 4 + 2], kv.z, a2);
                        a3 = fmaf(xqc[c4 * 4 + 3], kv.w, a3);
                    }
                    D[dh * 5 + dw] += (a0 + a1) + (a2 + a3);
                }
            }
#pragma unroll
            for (int q = 0; q < 9; ++q) {
                float a = Aq[q];
#pragma unroll
                for (int c = 0; c < CHUNK; ++c)
                    a = fmaf(xqc[c], kpe[q * 64 + cc * CHUNK + c], a);
                Aq[q] = a;
            }
        }
    }

    // ================= Softmax: Wt[25], Sq[9] =================
    float Wt[25];
    float Sq[9];
#pragma unroll
    for (int i = 0; i < 25; ++i) Wt[i] = 0.f;
#pragma unroll
    for (int i = 0; i < 9; ++i) Sq[i] = 0.f;

    if (act) {
#pragma unroll
        for (int ph = 0; ph < 3; ++ph) {
#pragma unroll
            for (int pw = 0; pw < 3; ++pw) {
                if ((h >= ph) && (h <= (H_ - 3) + ph) && (w >= pw) && (w <= (W_ - 3) + pw)) {
                    const int p = ph * 3 + pw;
                    float l[9];
                    float m = -1e30f;
#pragma unroll
                    for (int qh = 0; qh < 3; ++qh) {
#pragma unroll
                        for (int qw = 0; qw < 3; ++qw) {
                            const int q  = qh * 3 + qw;
                            const int nb = (ty + 2 + qh - ph) * HALO_COLS + (tx + 2 + qw - pw);
                            const float lv = D[(qh - ph + 2) * 5 + (qw - pw + 2)]
                                           + Aq[q] + sBT[p * HALO_N + nb] + Cc[p * 9 + q];
                            l[q] = lv;
                            m = fmaxf(m, lv);
                        }
                    }
                    float e[9];
                    float s = 0.f;
#pragma unroll
                    for (int q = 0; q < 9; ++q) { e[q] = __expf(l[q] - m); s += e[q]; }
                    const float inv = 1.0f / s;
#pragma unroll
                    for (int qh = 0; qh < 3; ++qh) {
#pragma unroll
                        for (int qw = 0; qw < 3; ++qw) {
                            const int q = qh * 3 + qw;
                            const float t = e[q] * inv;
                            Wt[(qh - ph + 2) * 5 + (qw - pw + 2)] += t;
                            Sq[q] += t;
                        }
                    }
                }
            }
        }
    }

    const int chh = min(h, H_ - 3) - max(0, h - 2) + 1;
    const int cww = min(w, W_ - 3) - max(0, w - 2) + 1;
    const float invN = 1.0f / (float)(chh * cww);
    float* ob = out + ((size_t)b * 128 + 64) * HW_ + h * W_ + w;

    // ================= Phase 2: PV, channel-chunked =================
    for (int cc = 0; cc < NCHUNK; ++cc) {
        __syncthreads();   // prior consumers done with sK
        for (int idx = tid; idx < HALO_N * 4; idx += 256) {
            const int nb = idx >> 2, s = idx & 3;
            const int hr = nb / HALO_COLS, hc = nb - hr * HALO_COLS;
            const int gh = min(max(h0 - 2 + hr, 0), H_ - 1);
            const int gw = min(max(w0 - 2 + hc, 0), W_ - 1);
            const float4 v = *(const float4*)(Xv + ((size_t)(bBase + gh * W_ + gw) << 6)
                                              + cc * CHUNK + (s << 2));
            *(float4*)(sK + nb * CHUNK + (((s ^ nb) & 3) << 2)) = v;
        }
        __syncthreads();

        if (act) {
            float o[CHUNK];
#pragma unroll
            for (int c = 0; c < CHUNK; ++c) o[c] = 0.f;

#pragma unroll
            for (int dh = 0; dh < 5; ++dh) {
#pragma unroll
                for (int dw = 0; dw < 5; ++dw) {
                    const float wt = Wt[dh * 5 + dw];
                    const int nb = (ty + dh) * HALO_COLS + (tx + dw);
                    const int kk = nb & 3;
                    const float* vb = sK + nb * CHUNK;
#pragma unroll
                    for (int c4 = 0; c4 < 4; ++c4) {
                        const float4 vv = *(const float4*)(vb + ((c4 ^ kk) << 2));
                        o[c4 * 4 + 0] = fmaf(wt, vv.x, o[c4 * 4 + 0]);
                        o[c4 * 4 + 1] = fmaf(wt, vv.y, o[c4 * 4 + 1]);
                        o[c4 * 4 + 2] = fmaf(wt, vv.z, o[c4 * 4 + 2]);
                        o[c4 * 4 + 3] = fmaf(wt, vv.w, o[c4 * 4 + 3]);
                    }
                }
            }
#pragma unroll
            for (int q = 0; q < 9; ++q) {
                const float sq = Sq[q];
#pragma unroll
                for (int c = 0; c < CHUNK; ++c)
                    o[c] = fmaf(sq, vpe[q * 64 + cc * CHUNK + c], o[c]);
            }
#pragma unroll
            for (int c = 0; c < CHUNK; ++c)
                ob[(size_t)(cc * CHUNK + c) * HW_] = o[c] * invN;
        }
    }
}

// ---------------------------------------------------------------------------
extern "C" void kernel_launch(void* const* d_in, const int* in_sizes, int n_in,
                              void* d_out, int out_size, void* d_ws, size_t ws_size,
                              hipStream_t stream)
{
    const float* x  = (const float*)d_in[0];
    const float* Wq = (const float*)d_in[1];
    const float* bq = (const float*)d_in[2];
    const float* Wk = (const float*)d_in[3];
    const float* bk = (const float*)d_in[4];
    const float* Wv = (const float*)d_in[5];
    const float* bv = (const float*)d_in[6];
    float* out = (float*)d_out;

    float* ws   = (float*)d_ws;
    float* Xk   = ws;
    float* Xv   = ws + (size_t)NPIX_ * 64;
    float* Bkv  = ws + (size_t)NPIX_ * 128;
    float* tabs = Bkv + (size_t)NPIX_ * 12;
    // total ws need: (128 + 12)*NPIX_ + TAB_SZ floats ≈ 324 MB

    tab_kernel<<<1, 64, 0, stream>>>(Wq, bq, Wk, bk, Wv, bv, tabs);

    proj_kernel<<<(NPIX_ + 255) / 256, 256, 0, stream>>>(
        x, Wk, Wv, tabs, Xk, Xv, Bkv, out);

    mega_kernel<<<dim3((W_ + 15) / 16, (H_ + 15) / 16, B_), 256, 0, stream>>>(
        x, Wq, Xk, Xv, Bkv, tabs, out);
}